// Round 1
// baseline (63.497 us; speedup 1.0000x reference)
//
#include <hip/hip_runtime.h>

#define H 2048
#define W 2048
#define NBINS 256

typedef unsigned int u32;

// ---------------- Kernel 1: per-tile histogram ----------------
// 384 tiles (b,c,ty,tx), each 256x256. 4 blocks per tile (64 rows each).
// Wave-private LDS histograms -> merge -> global atomicAdd.
__global__ __launch_bounds__(256) void clahe_hist(const float* __restrict__ x,
                                                  u32* __restrict__ hist) {
    int blk  = blockIdx.x;      // tile*4 + q
    int tile = blk >> 2;
    int q    = blk & 3;
    int tx   = tile & 7;
    int ty   = (tile >> 3) & 7;
    int img  = tile >> 6;       // b*C + c
    const float* base = x + (size_t)img * H * W;
    int row0 = ty * 256 + q * 64;
    int col0 = tx * 256;

    __shared__ u32 lh[4][NBINS];
    int t = threadIdx.x;
    for (int i = t; i < 4 * NBINS; i += 256) ((u32*)lh)[i] = 0;
    __syncthreads();

    int w  = t >> 6;    // wave id 0..3
    int cg = t & 63;    // 64 lanes cover 256 cols via float4
    for (int it = 0; it < 16; ++it) {
        int row = row0 + w + 4 * it;
        float4 v = *(const float4*)(base + (size_t)row * W + col0 + cg * 4);
        // bins = clip(floor(x*256), 0, 255); x >= 0 so trunc == floor
        int b0 = min((int)(v.x * 256.0f), 255);
        int b1 = min((int)(v.y * 256.0f), 255);
        int b2 = min((int)(v.z * 256.0f), 255);
        int b3 = min((int)(v.w * 256.0f), 255);
        atomicAdd(&lh[w][b0], 1u);
        atomicAdd(&lh[w][b1], 1u);
        atomicAdd(&lh[w][b2], 1u);
        atomicAdd(&lh[w][b3], 1u);
    }
    __syncthreads();
    u32 s = lh[0][t] + lh[1][t] + lh[2][t] + lh[3][t];
    atomicAdd(&hist[tile * NBINS + t], s);
}

// ---------------- Kernel 2: clip + cumsum -> LUT ----------------
// One block (256 threads) per tile; thread t owns bin t.
__global__ __launch_bounds__(256) void clahe_lut(const u32* __restrict__ hist,
                                                 float* __restrict__ luts) {
    int tile = blockIdx.x;
    int t = threadIdx.x;
    float h = (float)hist[tile * NBINS + t];
    float v = fminf(h, 10240.0f);   // max_val = max(int(40*65536)//256, 1)

    int lane = t & 63, wid = t >> 6;
    // wave inclusive scan
    #pragma unroll
    for (int off = 1; off < 64; off <<= 1) {
        float n = __shfl_up(v, off, 64);
        if (lane >= off) v += n;
    }
    __shared__ float wsum[4];
    __shared__ float tot;
    if (lane == 63) wsum[wid] = v;
    __syncthreads();
    float add = 0.0f;
    for (int ww = 0; ww < wid; ++ww) add += wsum[ww];
    v += add;                        // inclusive cumsum of clipped
    if (t == 255) tot = v;           // total of clipped
    __syncthreads();

    float e   = (65536.0f - tot) * (1.0f / 256.0f);   // excess/num_bins
    float cum = v + (float)(t + 1) * e;               // cumsum(clipped + e)
    float lut = floorf(fminf(fmaxf(cum * (255.0f / 65536.0f), 0.0f), 255.0f));
    luts[tile * NBINS + t] = lut;
}

// ---------------- Kernel 3: bilinear LUT apply ----------------
// Block = 128 cols x 64 rows region (aligned so the (y0,x0) cell is constant).
// Stage the 4 LUTs in LDS; float4 in / float4 out.
__global__ __launch_bounds__(256) void clahe_apply(const float* __restrict__ x,
                                                   const float* __restrict__ luts,
                                                   float* __restrict__ out) {
    int rx  = blockIdx.x * 128;
    int ry  = blockIdx.y * 64;
    int img = blockIdx.z;

    // cell indices from the region center (constant over the whole region)
    int yc = ry + 32, xc = rx + 64;
    int y0 = min(max((int)floorf((yc + 0.5f) * (1.0f / 256.0f) - 0.5f), 0), 7);
    int x0 = min(max((int)floorf((xc + 0.5f) * (1.0f / 256.0f) - 0.5f), 0), 7);
    int y1 = min(y0 + 1, 7), x1 = min(x0 + 1, 7);

    const float* lb = luts + (size_t)img * 64 * NBINS;
    __shared__ float l00[NBINS], l01[NBINS], l10[NBINS], l11[NBINS];
    int t = threadIdx.x;
    l00[t] = lb[(y0 * 8 + x0) * NBINS + t];
    l01[t] = lb[(y0 * 8 + x1) * NBINS + t];
    l10[t] = lb[(y1 * 8 + x0) * NBINS + t];
    l11[t] = lb[(y1 * 8 + x1) * NBINS + t];
    __syncthreads();

    const float* base  = x   + (size_t)img * H * W;
    float*       obase = out + (size_t)img * H * W;

    int cg = t & 31, rg = t >> 5;
    int col = rx + cg * 4;

    float fx0 = (float)x0;
    float wxa[4];
    #pragma unroll
    for (int k = 0; k < 4; ++k) {
        float xs = (col + k + 0.5f) * (1.0f / 256.0f) - 0.5f;
        xs = fminf(fmaxf(xs, 0.0f), 7.0f);
        wxa[k] = xs - fx0;
    }

    #pragma unroll
    for (int it = 0; it < 8; ++it) {
        int row = ry + rg + 8 * it;
        float ys = (row + 0.5f) * (1.0f / 256.0f) - 0.5f;
        ys = fminf(fmaxf(ys, 0.0f), 7.0f);
        float wy = ys - (float)y0;

        float4 v = *(const float4*)(base + (size_t)row * W + col);
        float vv[4] = {v.x, v.y, v.z, v.w};
        float r[4];
        #pragma unroll
        for (int k = 0; k < 4; ++k) {
            int p = min((int)(vv[k] * 255.0f), 255);   // pbin = clip(floor(x*255),0,255)
            float wx = wxa[k];
            float ix0 = (1.0f - wx) * l00[p] + wx * l01[p];
            float ix1 = (1.0f - wx) * l10[p] + wx * l11[p];
            r[k] = ((1.0f - wy) * ix0 + wy * ix1) * (1.0f / 255.0f);
        }
        float4 o; o.x = r[0]; o.y = r[1]; o.z = r[2]; o.w = r[3];
        *(float4*)(obase + (size_t)row * W + col) = o;
    }
}

extern "C" void kernel_launch(void* const* d_in, const int* in_sizes, int n_in,
                              void* d_out, int out_size, void* d_ws, size_t ws_size,
                              hipStream_t stream) {
    const float* x = (const float*)d_in[0];
    float* out = (float*)d_out;

    u32*   hist = (u32*)d_ws;                 // 384*256 u32  = 384 KB
    float* luts = (float*)d_ws + 384 * NBINS; // 384*256 f32  = 384 KB

    hipMemsetAsync(hist, 0, 384 * NBINS * sizeof(u32), stream);

    clahe_hist<<<dim3(384 * 4), dim3(256), 0, stream>>>(x, hist);
    clahe_lut<<<dim3(384), dim3(256), 0, stream>>>(hist, luts);
    clahe_apply<<<dim3(16, 32, 6), dim3(256), 0, stream>>>(x, luts, out);
}

// Round 2
// 53.580 us; speedup vs baseline: 1.1851x; 1.1851x over previous
//
#include <hip/hip_runtime.h>

#define H 2048
#define W 2048
#define NBINS 256
#define NIMG 6
#define NTILE 384            // 6 imgs * 64 tiles
#define IMGPX (H * W)

typedef unsigned int u32;
typedef unsigned char u8;

// ---------------- Kernel 1: per-tile partial histograms + pbin ----------------
// 1536 blocks = 4 per tile (64 rows each). Wave-private LDS hists -> plain
// store of the block's partial histogram (no memset, no global atomics).
// Also emits pbin = clip(floor(x*255),0,255) as packed u8 (image layout).
template <bool WRITE_PBIN>
__global__ __launch_bounds__(256) void clahe_hist(const float* __restrict__ x,
                                                  u32* __restrict__ part,
                                                  u8* __restrict__ pbin) {
    int blk  = blockIdx.x;      // tile*4 + q
    int tile = blk >> 2;
    int q    = blk & 3;
    int tx   = tile & 7;
    int ty   = (tile >> 3) & 7;
    int img  = tile >> 6;
    const float* base = x + (size_t)img * IMGPX;
    u8* pb = pbin + (size_t)img * IMGPX;
    int row0 = ty * 256 + q * 64;
    int col0 = tx * 256;

    __shared__ u32 lh[4][NBINS];
    int t = threadIdx.x;
    for (int i = t; i < 4 * NBINS; i += 256) ((u32*)lh)[i] = 0;
    __syncthreads();

    int w  = t >> 6;    // wave id 0..3
    int cg = t & 63;    // 64 lanes cover 256 cols via float4
    for (int it = 0; it < 16; ++it) {
        int row = row0 + w + 4 * it;
        size_t off = (size_t)row * W + col0 + cg * 4;
        float4 v = *(const float4*)(base + off);
        // hist bins = clip(floor(x*256), 0, 255); x >= 0 so trunc == floor
        int b0 = min((int)(v.x * 256.0f), 255);
        int b1 = min((int)(v.y * 256.0f), 255);
        int b2 = min((int)(v.z * 256.0f), 255);
        int b3 = min((int)(v.w * 256.0f), 255);
        atomicAdd(&lh[w][b0], 1u);
        atomicAdd(&lh[w][b1], 1u);
        atomicAdd(&lh[w][b2], 1u);
        atomicAdd(&lh[w][b3], 1u);
        if (WRITE_PBIN) {
            // pbin = clip(floor(x*255), 0, 255)
            u32 p0 = min((int)(v.x * 255.0f), 255);
            u32 p1 = min((int)(v.y * 255.0f), 255);
            u32 p2 = min((int)(v.z * 255.0f), 255);
            u32 p3 = min((int)(v.w * 255.0f), 255);
            *(u32*)(pb + off) = p0 | (p1 << 8) | (p2 << 16) | (p3 << 24);
        }
    }
    __syncthreads();
    part[(size_t)blk * NBINS + t] =
        lh[0][t] + lh[1][t] + lh[2][t] + lh[3][t];
}

// ---------------- Kernel 2: sum partials, clip + cumsum -> LUT ----------------
// One block (256 threads) per tile; thread t owns bin t. LUT already /255.
__global__ __launch_bounds__(256) void clahe_lut(const u32* __restrict__ part,
                                                 float* __restrict__ luts) {
    int tile = blockIdx.x;
    int t = threadIdx.x;
    const u32* p = part + (size_t)tile * 4 * NBINS;
    float h = (float)(p[t] + p[NBINS + t] + p[2 * NBINS + t] + p[3 * NBINS + t]);
    float v = fminf(h, 10240.0f);   // max_val = max(int(40*65536)//256, 1)

    int lane = t & 63, wid = t >> 6;
    #pragma unroll
    for (int off = 1; off < 64; off <<= 1) {
        float n = __shfl_up(v, off, 64);
        if (lane >= off) v += n;
    }
    __shared__ float wsum[4];
    __shared__ float tot;
    if (lane == 63) wsum[wid] = v;
    __syncthreads();
    float add = 0.0f;
    for (int ww = 0; ww < wid; ++ww) add += wsum[ww];
    v += add;                        // inclusive cumsum of clipped
    if (t == 255) tot = v;
    __syncthreads();

    float e   = (65536.0f - tot) * (1.0f / 256.0f);   // excess/num_bins
    float cum = v + (float)(t + 1) * e;               // cumsum(clipped + e)
    float lut = floorf(fminf(fmaxf(cum * (255.0f / 65536.0f), 0.0f), 255.0f));
    luts[(size_t)tile * NBINS + t] = lut * (1.0f / 255.0f);  // fold /255
}

// ---------------- Kernel 3: bilinear LUT apply ----------------
// Block = 128 cols x 64 rows (aligned so the (y0,x0) cell is constant).
// 8 px/thread. USE_PBIN: read packed u8 bins; else re-read x and bin inline.
template <bool USE_PBIN>
__global__ __launch_bounds__(256) void clahe_apply(const float* __restrict__ x,
                                                   const u8* __restrict__ pbin,
                                                   const float* __restrict__ luts,
                                                   float* __restrict__ out) {
    int rx  = blockIdx.x * 128;
    int ry  = blockIdx.y * 64;
    int img = blockIdx.z;

    int yc = ry + 32, xc = rx + 64;
    int y0 = min(max((int)floorf((yc + 0.5f) * (1.0f / 256.0f) - 0.5f), 0), 7);
    int x0 = min(max((int)floorf((xc + 0.5f) * (1.0f / 256.0f) - 0.5f), 0), 7);
    int y1 = min(y0 + 1, 7), x1 = min(x0 + 1, 7);

    const float* lb = luts + (size_t)img * 64 * NBINS;
    __shared__ float l00[NBINS], l01[NBINS], l10[NBINS], l11[NBINS];
    int t = threadIdx.x;
    l00[t] = lb[(y0 * 8 + x0) * NBINS + t];
    l01[t] = lb[(y0 * 8 + x1) * NBINS + t];
    l10[t] = lb[(y1 * 8 + x0) * NBINS + t];
    l11[t] = lb[(y1 * 8 + x1) * NBINS + t];
    __syncthreads();

    const float* base  = x    + (size_t)img * IMGPX;
    const u8*    pbase = pbin + (size_t)img * IMGPX;
    float*       obase = out  + (size_t)img * IMGPX;

    int cg = t & 15, rg = t >> 4;     // 16 threads * 8 px = 128 cols; 16 rows
    int col = rx + cg * 8;

    float fx0 = (float)x0;
    float wxa[8];
    #pragma unroll
    for (int k = 0; k < 8; ++k) {
        float xs = (col + k + 0.5f) * (1.0f / 256.0f) - 0.5f;
        xs = fminf(fmaxf(xs, 0.0f), 7.0f);
        wxa[k] = xs - fx0;
    }

    #pragma unroll
    for (int it = 0; it < 4; ++it) {
        int row = ry + rg + 16 * it;
        float ys = (row + 0.5f) * (1.0f / 256.0f) - 0.5f;
        ys = fminf(fmaxf(ys, 0.0f), 7.0f);
        float wy = ys - (float)y0;

        size_t off = (size_t)row * W + col;
        int p[8];
        if (USE_PBIN) {
            uint2 u = *(const uint2*)(pbase + off);
            #pragma unroll
            for (int k = 0; k < 4; ++k) {
                p[k]     = (u.x >> (8 * k)) & 255;
                p[k + 4] = (u.y >> (8 * k)) & 255;
            }
        } else {
            float4 a = *(const float4*)(base + off);
            float4 b = *(const float4*)(base + off + 4);
            p[0] = min((int)(a.x * 255.0f), 255);
            p[1] = min((int)(a.y * 255.0f), 255);
            p[2] = min((int)(a.z * 255.0f), 255);
            p[3] = min((int)(a.w * 255.0f), 255);
            p[4] = min((int)(b.x * 255.0f), 255);
            p[5] = min((int)(b.y * 255.0f), 255);
            p[6] = min((int)(b.z * 255.0f), 255);
            p[7] = min((int)(b.w * 255.0f), 255);
        }

        float r[8];
        #pragma unroll
        for (int k = 0; k < 8; ++k) {
            float wx = wxa[k];
            float ix0 = (1.0f - wx) * l00[p[k]] + wx * l01[p[k]];
            float ix1 = (1.0f - wx) * l10[p[k]] + wx * l11[p[k]];
            r[k] = (1.0f - wy) * ix0 + wy * ix1;   // /255 folded into LUT
        }
        float4 o0 = {r[0], r[1], r[2], r[3]};
        float4 o1 = {r[4], r[5], r[6], r[7]};
        *(float4*)(obase + off)     = o0;
        *(float4*)(obase + off + 4) = o1;
    }
}

extern "C" void kernel_launch(void* const* d_in, const int* in_sizes, int n_in,
                              void* d_out, int out_size, void* d_ws, size_t ws_size,
                              hipStream_t stream) {
    const float* x = (const float*)d_in[0];
    float* out = (float*)d_out;

    const size_t PBIN_BYTES = (size_t)NIMG * IMGPX;           // 25.17 MB
    const size_t PART_BYTES = (size_t)NTILE * 4 * NBINS * 4;  // 1.57 MB
    const size_t LUT_BYTES  = (size_t)NTILE * NBINS * 4;      // 0.39 MB
    bool use_pbin = ws_size >= PBIN_BYTES + PART_BYTES + LUT_BYTES;

    u8*    pbin;
    u32*   part;
    float* luts;
    if (use_pbin) {
        pbin = (u8*)d_ws;
        part = (u32*)((char*)d_ws + PBIN_BYTES);
        luts = (float*)((char*)d_ws + PBIN_BYTES + PART_BYTES);
    } else {
        pbin = (u8*)d_ws;   // unused
        part = (u32*)d_ws;
        luts = (float*)((char*)d_ws + PART_BYTES);
    }

    if (use_pbin)
        clahe_hist<true><<<dim3(NTILE * 4), dim3(256), 0, stream>>>(x, part, pbin);
    else
        clahe_hist<false><<<dim3(NTILE * 4), dim3(256), 0, stream>>>(x, part, pbin);

    clahe_lut<<<dim3(NTILE), dim3(256), 0, stream>>>(part, luts);

    if (use_pbin)
        clahe_apply<true><<<dim3(16, 32, NIMG), dim3(256), 0, stream>>>(x, pbin, luts, out);
    else
        clahe_apply<false><<<dim3(16, 32, NIMG), dim3(256), 0, stream>>>(x, pbin, luts, out);
}